// Round 10
// baseline (324.631 us; speedup 1.0000x reference)
//
#include <hip/hip_runtime.h>
#include <cstdint>
#include <cstddef>

using frag8 = __attribute__((ext_vector_type(8))) short;   // 8 bf16
using f32x4 = __attribute__((ext_vector_type(4))) float;

__device__ __forceinline__ float b2f_bits(unsigned short u) {
    union { uint32_t u32; float f; } x; x.u32 = ((uint32_t)u) << 16; return x.f;
}
__device__ __forceinline__ float b2f_lo(uint32_t pk) {
    return __builtin_bit_cast(float, pk << 16);
}
__device__ __forceinline__ float b2f_hi(uint32_t pk) {
    return __builtin_bit_cast(float, pk & 0xffff0000u);
}
__device__ __forceinline__ unsigned short f2b(float f) {   // RNE f32 -> bf16
    uint32_t u = __builtin_bit_cast(uint32_t, f);
    uint32_t r = (u + 0x7fffu + ((u >> 16) & 1u)) >> 16;
    return (unsigned short)r;
}

#define HF 32
#define WFEAT 88
#define NCAM 6
#define NPT 102400
#define BM 128
#define BN 128
#define BK 64

// ================= merged prep: project + transposes + casts + w1 pack =================
// grid = 2400 (project) + 8448 (featT: 6*128*32*88 = 2,162,688 = 8448*256) + 256 (w2T)
//        + 128 (w3T) + 1024 + 256 + 64 (casts) + 1 (w1 pack) = 12577 blocks x 256
__global__ __launch_bounds__(256) void k_prep(const float* __restrict__ feat,
                                              const float* __restrict__ pw2,
                                              const float* __restrict__ pw3,
                                              const float* __restrict__ c1w,
                                              const float* __restrict__ c2w,
                                              const float* __restrict__ c3w,
                                              const float* __restrict__ pw1,
                                              const float* __restrict__ pb1,
                                              const float* __restrict__ l2i,
                                              const float* __restrict__ bev,
                                              unsigned short* __restrict__ featT,
                                              unsigned short* __restrict__ W2Tb,
                                              unsigned short* __restrict__ W3Tb,
                                              unsigned short* __restrict__ C1Wb,
                                              unsigned short* __restrict__ C2Wb,
                                              unsigned short* __restrict__ C3Wb,
                                              float* __restrict__ w1p,
                                              int* __restrict__ poff,
                                              float4* __restrict__ pwts) {
    int b = blockIdx.x, t = threadIdx.x;
    if (b < 2400) {                       // ---- projection precompute (cam, point) ----
        int idx = b * 256 + t;            // n*NPT + pt, < 614400
        int n = idx / NPT, pt = idx - n * NPT;
        int q = pt >> 2, p = pt & 3;
        int h = q / 160, w = q - h * 160;
        const float* bv = bev + ((p * 160 + h) * 160 + w) * 3;
        float rx = bv[0] * 100.f - 50.f;
        float ry = bv[1] * 100.f - 50.f;
        float rz = bv[2] * 8.f - 4.f;
        const float* M = l2i + n * 16;
        float c0   = M[0] * rx + M[1] * ry + M[2]  * rz + M[3];
        float c1v  = M[4] * rx + M[5] * ry + M[6]  * rz + M[7];
        float homo = M[8] * rx + M[9] * ry + M[10] * rz + M[11];
        float z = fmaxf(homo, 1e-5f);
        float u = c0 / z / 704.0f;
        float v = c1v / z / 256.0f;
        if (!(homo > 1e-5f && u > 0.f && u < 1.f && v > 0.f && v < 1.f)) {
            poff[idx] = -1;
            return;
        }
        float fx = u * (float)WFEAT - 0.5f;
        float fy = v * (float)HF - 0.5f;
        float fx0 = floorf(fx), fy0 = floorf(fy);
        float dx = fx - fx0, dy = fy - fy0;
        int x0 = (int)fx0, y0 = (int)fy0;
        float wxa = (x0 < 0) ? dx : 1.f - dx;
        float wxb = (x0 >= 0 && x0 < WFEAT - 1) ? dx : 0.f;
        float wya = (y0 < 0) ? dy : 1.f - dy;
        float wyb = (y0 >= 0 && y0 < HF - 1) ? dy : 0.f;
        int bx = max(x0, 0), by = max(y0, 0);
        poff[idx] = ((n * HF + by) * WFEAT + bx) << 7;
        pwts[idx] = make_float4(wxa * wya, wxb * wya, wxa * wyb, wxb * wyb);
        return;
    }
    b -= 2400;
    if (b < 8448) {                       // ---- feat -> featT (channel-last bf16) ----
        int idx = b * 256 + t;            // < 2,162,688 exactly
        int c = idx & 127;
        int rest = idx >> 7;
        int x = rest % WFEAT; rest /= WFEAT;
        int y = rest % HF;
        int n = rest / HF;
        featT[idx] = f2b(feat[((n * 128 + c) * HF + y) * WFEAT + x]);
        return;
    }
    b -= 8448;
    if (b < 256) {                        // ---- pw2 [256][256] -> W2Tb [o][k] ----
        int idx = b * 256 + t;
        int r = idx >> 8, c = idx & 255;
        W2Tb[c * 256 + r] = f2b(pw2[idx]);
        return;
    }
    b -= 256;
    if (b < 128) {                        // ---- pw3 [256][128] -> W3Tb [o][k] ----
        int idx = b * 256 + t;
        int r = idx >> 7, c = idx & 127;
        W3Tb[c * 256 + r] = f2b(pw3[idx]);
        return;
    }
    b -= 128;
    if (b < 1024) { int idx = b * 256 + t; C1Wb[idx] = f2b(c1w[idx]); return; }
    b -= 1024;
    if (b < 256)  { int idx = b * 256 + t; C2Wb[idx] = f2b(c2w[idx]); return; }
    b -= 256;
    if (b < 64)   { int idx = b * 256 + t; C3Wb[idx] = f2b(c3w[idx]); return; }
    // ---- w1 pack: w1p[o] = (w1[0][o], w1[1][o], w1[2][o], b1[o]) ----
    w1p[t * 4 + 0] = pw1[t];
    w1p[t * 4 + 1] = pw1[256 + t];
    w1p[t * 4 + 2] = pw1[512 + t];
    w1p[t * 4 + 3] = pb1[t];
}

// ---------------- gather-only sampling: one wave per point, lane = 2 channels ----------------
__global__ __launch_bounds__(256) void k_sample2(const unsigned short* __restrict__ featT,
                                                 const int* __restrict__ poff,
                                                 const float4* __restrict__ pwts,
                                                 unsigned short* __restrict__ samp) {
    int pt = blockIdx.x * 4 + (threadIdx.x >> 6);
    int lane = threadIdx.x & 63;
    int c2 = lane * 2;
    int offs[NCAM];
    float4 ww[NCAM];
    #pragma unroll
    for (int n = 0; n < NCAM; ++n) offs[n] = poff[n * NPT + pt];
    #pragma unroll
    for (int n = 0; n < NCAM; ++n) ww[n] = pwts[n * NPT + pt];   // garbage if invalid; unused
    float acc0 = 0.f, acc1 = 0.f;
    #pragma unroll
    for (int n = 0; n < NCAM; ++n) {
        if (offs[n] >= 0) {                        // wave-uniform scalar branch
            const unsigned short* base = featT + offs[n] + c2;
            uint32_t p00 = *(const uint32_t*)(base);
            uint32_t p01 = *(const uint32_t*)(base + 128);
            uint32_t p10 = *(const uint32_t*)(base + WFEAT * 128);
            uint32_t p11 = *(const uint32_t*)(base + WFEAT * 128 + 128);
            float4 w = ww[n];
            acc0 += w.x * b2f_lo(p00) + w.y * b2f_lo(p01) + w.z * b2f_lo(p10) + w.w * b2f_lo(p11);
            acc1 += w.x * b2f_hi(p00) + w.y * b2f_hi(p01) + w.z * b2f_hi(p10) + w.w * b2f_hi(p11);
        }
    }
    uint32_t outpk = (uint32_t)f2b(acc0) | ((uint32_t)f2b(acc1) << 16);
    *(uint32_t*)(samp + (size_t)pt * 128 + c2) = outpk;
}

// ================= 1024-thread (16-wave) GEMM: 256x256 tile, BK=32, dbuf =================
// LDS tile 256 rows x 32 cols bf16 = 16 KB; chunk = 8 bf16 = 16 B; slot = chunk ^ ((row>>1)&3)
__device__ __forceinline__ void stage_tile_big(const unsigned short* __restrict__ g, int ld,
                                               unsigned short* lds, int t) {
    int r = t >> 2, cs = t & 3;
    int cl = cs ^ ((r >> 1) & 3);                  // logical chunk held by slot (r,cs)
    __builtin_amdgcn_global_load_lds(
        (const __attribute__((address_space(1))) void*)(g + (size_t)r * ld + cl * 8),
        (__attribute__((address_space(3))) void*)(lds + (t >> 6) * 512),   // wave-uniform base
        16, 0, 0);
}

__device__ __forceinline__ frag8 frag_read_big(const unsigned short* lds, int row, int chunk) {
    return *(const frag8*)(lds + row * 32 + ((chunk ^ ((row >> 1) & 3)) << 3));
}

__device__ __forceinline__ void mma_tile_big(const unsigned short* As, const unsigned short* Bs,
                                             int wm, int wn, int lane, f32x4 (&acc)[4][4]) {
    int lm = lane & 15, lq = lane >> 4;            // lq = k-chunk 0..3
    frag8 a[4], b[4];
    #pragma unroll
    for (int t = 0; t < 4; ++t) a[t] = frag_read_big(As, wm * 64 + t * 16 + lm, lq);
    #pragma unroll
    for (int t = 0; t < 4; ++t) b[t] = frag_read_big(Bs, wn * 64 + t * 16 + lm, lq);
    #pragma unroll
    for (int tm = 0; tm < 4; ++tm)
        #pragma unroll
        for (int tn = 0; tn < 4; ++tn)
            acc[tm][tn] = __builtin_amdgcn_mfma_f32_16x16x32_bf16(a[tm], b[tn], acc[tm][tn], 0, 0, 0);
}

// pe2 with fused pe1: A-tile (H1 values) computed in registers from w1p, ds_write staged.
// One chunk per thread per kt: 8 float4 table loads + ~40 VALU.
__global__ __launch_bounds__(1024) void k_gemm_pe2f(const float* __restrict__ bev,
                                                    const float* __restrict__ w1p,
                                                    const unsigned short* __restrict__ Bt,
                                                    const float* __restrict__ bias,
                                                    unsigned short* __restrict__ H2) {
    __shared__ unsigned short As[2][256 * 32], Bs[2][256 * 32];
    int t = threadIdx.x, lane = t & 63, wid = t >> 6;
    int wm = wid >> 2, wn = wid & 3;
    int m0 = blockIdx.x * 256;
    // A-staging identity: row r, slot cs, logical chunk cl (matches frag_read_big swizzle)
    int r = t >> 2, cs = t & 3;
    int cl = cs ^ ((r >> 1) & 3);
    int m = m0 + r;
    int q = m >> 2, p = m & 3;
    int h = q / 160, w = q - h * 160;
    const float* bv = bev + ((p * 160 + h) * 160 + w) * 3;
    float cx = bv[0], cy = bv[1], cz = bv[2];

    f32x4 acc[4][4] = {};
    // stage kt=0
    {
        int o = cl * 8;
        union { unsigned short u[8]; frag8 v; } pk;
        #pragma unroll
        for (int j = 0; j < 8; ++j) {
            float4 wv = *(const float4*)(w1p + (o + j) * 4);
            float a = fmaf(cx, wv.x, fmaf(cy, wv.y, fmaf(cz, wv.z, wv.w)));
            pk.u[j] = f2b(fmaxf(a, 0.f));
        }
        *(frag8*)(&As[0][r * 32 + cs * 8]) = pk.v;
    }
    stage_tile_big(Bt, 256, Bs[0], t);
    __syncthreads();
    #pragma unroll
    for (int kt = 0; kt < 8; ++kt) {
        int cur = kt & 1, nxt = cur ^ 1;
        if (kt + 1 < 8) {
            int o = (kt + 1) * 32 + cl * 8;
            union { unsigned short u[8]; frag8 v; } pk;
            #pragma unroll
            for (int j = 0; j < 8; ++j) {
                float4 wv = *(const float4*)(w1p + (o + j) * 4);
                float a = fmaf(cx, wv.x, fmaf(cy, wv.y, fmaf(cz, wv.z, wv.w)));
                pk.u[j] = f2b(fmaxf(a, 0.f));
            }
            *(frag8*)(&As[nxt][r * 32 + cs * 8]) = pk.v;
            stage_tile_big(Bt + (kt + 1) * 32, 256, Bs[nxt], t);
        }
        mma_tile_big(As[cur], Bs[cur], wm, wn, lane, acc);
        __syncthreads();
    }
    int lm = lane & 15, lq = lane >> 4;
    #pragma unroll
    for (int tn = 0; tn < 4; ++tn) {
        int n = wn * 64 + tn * 16 + lm;
        float bn = bias[n];
        #pragma unroll
        for (int tm = 0; tm < 4; ++tm) {
            int mb = m0 + wm * 64 + tm * 16 + lq * 4;
            #pragma unroll
            for (int rr = 0; rr < 4; ++rr)
                H2[(size_t)(mb + rr) * 256 + n] = f2b(fmaxf(acc[tm][tn][rr] + bn, 0.f));
        }
    }
}

template <int KT>
__device__ __forceinline__ void gemm_loop_big(const unsigned short* __restrict__ A, int ldA,
                                              const unsigned short* __restrict__ B, int ldB,
                                              unsigned short (*As)[256 * 32],
                                              unsigned short (*Bs)[256 * 32],
                                              int t, int wm, int wn, int lane,
                                              f32x4 (&acc)[4][4]) {
    stage_tile_big(A, ldA, As[0], t);
    stage_tile_big(B, ldB, Bs[0], t);
    __syncthreads();
    #pragma unroll
    for (int kt = 0; kt < KT; ++kt) {
        int cur = kt & 1, nxt = cur ^ 1;
        if (kt + 1 < KT) {                         // prefetch flies during mma
            stage_tile_big(A + (kt + 1) * 32, ldA, As[nxt], t);
            stage_tile_big(B + (kt + 1) * 32, ldB, Bs[nxt], t);
        }
        mma_tile_big(As[cur], Bs[cur], wm, wn, lane, acc);
        __syncthreads();
    }
}

// conv1 big: Y1 = X @ C1W^T + b, M=25600, N=512, K=512 -> grid(100,2), 1024 thr, fused stats
__global__ __launch_bounds__(1024) void k_gemm_conv1_big(const unsigned short* __restrict__ A,
                                                         const unsigned short* __restrict__ Bt,
                                                         const float* __restrict__ bias,
                                                         unsigned short* __restrict__ Y,
                                                         float* __restrict__ st) {
    __shared__ unsigned short As[2][256 * 32], Bs[2][256 * 32];
    int t = threadIdx.x, lane = t & 63, wid = t >> 6;
    int wm = wid >> 2, wn = wid & 3;
    int m0 = blockIdx.x * 256, n0 = blockIdx.y * 256;
    f32x4 acc[4][4] = {};
    gemm_loop_big<16>(A + (size_t)m0 * 512, 512, Bt + (size_t)n0 * 512, 512,
                      As, Bs, t, wm, wn, lane, acc);
    int lm = lane & 15, lq = lane >> 4;
    #pragma unroll
    for (int tn = 0; tn < 4; ++tn) {
        int n = n0 + wn * 64 + tn * 16 + lm;
        float bn = bias[n];
        float s1 = 0.f, s2 = 0.f;
        #pragma unroll
        for (int tm = 0; tm < 4; ++tm) {
            int mb = m0 + wm * 64 + tm * 16 + lq * 4;
            #pragma unroll
            for (int rr = 0; rr < 4; ++rr) {
                float v = acc[tm][tn][rr] + bn;
                Y[(size_t)(mb + rr) * 512 + n] = f2b(v);
                s1 += v; s2 += v * v;
            }
        }
        s1 += __shfl_xor(s1, 16); s1 += __shfl_xor(s1, 32);
        s2 += __shfl_xor(s2, 16); s2 += __shfl_xor(s2, 32);
        if (lq == 0) { atomicAdd(&st[n], s1); atomicAdd(&st[512 + n], s2); }
    }
}

// ================= 256-thread GEMM (single-buffer) =================
__device__ __forceinline__ void stage_tile(const unsigned short* __restrict__ g, int ld,
                                           unsigned short* lds, int wave, int lane) {
    #pragma unroll
    for (int j = 0; j < 4; ++j) {
        int idx = wave * 256 + j * 64 + lane;      // chunk slot index 0..1023
        int r = idx >> 3;
        int cs = idx & 7;
        int cl = cs ^ (r & 7);                     // logical chunk this slot holds
        __builtin_amdgcn_global_load_lds(
            (const __attribute__((address_space(1))) void*)(g + (size_t)r * ld + cl * 8),
            (__attribute__((address_space(3))) void*)(lds + wave * 2048 + j * 512),
            16, 0, 0);
    }
}

__device__ __forceinline__ frag8 frag_read(const unsigned short* lds, int row, int chunk) {
    return *(const frag8*)(lds + row * 64 + ((chunk ^ (row & 7)) << 3));
}

__device__ __forceinline__ void mma_tile(const unsigned short* As, const unsigned short* Bs,
                                         int wm, int wn, int lane, f32x4 (&acc)[4][4]) {
    int lm = lane & 15, lq = lane >> 4;
    #pragma unroll
    for (int kk = 0; kk < 2; ++kk) {
        frag8 a[4], b[4];
        #pragma unroll
        for (int t = 0; t < 4; ++t) a[t] = frag_read(As, wm * 64 + t * 16 + lm, kk * 4 + lq);
        #pragma unroll
        for (int t = 0; t < 4; ++t) b[t] = frag_read(Bs, wn * 64 + t * 16 + lm, kk * 4 + lq);
        #pragma unroll
        for (int tm = 0; tm < 4; ++tm)
            #pragma unroll
            for (int tn = 0; tn < 4; ++tn)
                acc[tm][tn] = __builtin_amdgcn_mfma_f32_16x16x32_bf16(a[tm], b[tn], acc[tm][tn], 0, 0, 0);
    }
}

// ---------------- pe3: X = bf16(samp + H2 @ W3T^T + b3) ----------------
__global__ __launch_bounds__(256) void k_gemm_pe3(const unsigned short* __restrict__ A,
                                                  const unsigned short* __restrict__ Bt,
                                                  const float* __restrict__ bias,
                                                  const unsigned short* __restrict__ samp,
                                                  unsigned short* __restrict__ X) {
    __shared__ unsigned short As[BM * BK], Bs[BN * BK];
    int lane = threadIdx.x & 63, wave = threadIdx.x >> 6;
    int wm = wave >> 1, wn = wave & 1;
    int m0 = blockIdx.x * BM;
    f32x4 acc[4][4] = {};
    for (int kt = 0; kt < 4; ++kt) {
        stage_tile(A + (size_t)m0 * 256 + kt * BK, 256, As, wave, lane);
        stage_tile(Bt + (size_t)kt * BK, 256, Bs, wave, lane);
        __syncthreads();
        mma_tile(As, Bs, wm, wn, lane, acc);
        __syncthreads();
    }
    int lm = lane & 15, lq = lane >> 4;
    #pragma unroll
    for (int tn = 0; tn < 4; ++tn) {
        int n = wn * 64 + tn * 16 + lm;
        float bn = bias[n];
        #pragma unroll
        for (int tm = 0; tm < 4; ++tm) {
            int mb = m0 + wm * 64 + tm * 16 + lq * 4;
            #pragma unroll
            for (int rr = 0; rr < 4; ++rr) {
                size_t off = (size_t)(mb + rr) * 128 + n;
                X[off] = f2b(acc[tm][tn][rr] + bn + b2f_bits(samp[off]));
            }
        }
    }
}

// ---------------- conv2 GEMM -> bf16 Y + f32 inorm stats ----------------
template <int K, bool STATS>
__global__ __launch_bounds__(256) void k_gemm_conv(const unsigned short* __restrict__ A,
                                                   const unsigned short* __restrict__ Bt,
                                                   const float* __restrict__ bias,
                                                   unsigned short* __restrict__ Y, int ldY,
                                                   float* __restrict__ st, int C) {
    __shared__ unsigned short As[BM * BK], Bs[BN * BK];
    int lane = threadIdx.x & 63, wave = threadIdx.x >> 6;
    int wm = wave >> 1, wn = wave & 1;
    int m0 = blockIdx.x * BM, n0 = blockIdx.y * BN;
    f32x4 acc[4][4] = {};
    for (int kt = 0; kt < K / BK; ++kt) {
        stage_tile(A + (size_t)m0 * K + kt * BK, K, As, wave, lane);
        stage_tile(Bt + (size_t)n0 * K + kt * BK, K, Bs, wave, lane);
        __syncthreads();
        mma_tile(As, Bs, wm, wn, lane, acc);
        __syncthreads();
    }
    int lm = lane & 15, lq = lane >> 4;
    #pragma unroll
    for (int tn = 0; tn < 4; ++tn) {
        int n = n0 + wn * 64 + tn * 16 + lm;
        float bn = bias[n];
        float s1 = 0.f, s2 = 0.f;
        #pragma unroll
        for (int tm = 0; tm < 4; ++tm) {
            int mb = m0 + wm * 64 + tm * 16 + lq * 4;
            #pragma unroll
            for (int rr = 0; rr < 4; ++rr) {
                float v = acc[tm][tn][rr] + bn;
                Y[(size_t)(mb + rr) * ldY + n] = f2b(v);
                if (STATS) { s1 += v; s2 += v * v; }
            }
        }
        if (STATS) {
            s1 += __shfl_xor(s1, 16); s1 += __shfl_xor(s1, 32);
            s2 += __shfl_xor(s2, 16); s2 += __shfl_xor(s2, 32);
            if (lq == 0) { atomicAdd(&st[n], s1); atomicAdd(&st[C + n], s2); }
        }
    }
}

// ---------------- conv3 -> out f32 [128][25600] ----------------
__global__ __launch_bounds__(256) void k_gemm_conv3(const unsigned short* __restrict__ A,
                                                    const unsigned short* __restrict__ Bt,
                                                    const float* __restrict__ bias,
                                                    float* __restrict__ out) {
    __shared__ unsigned short As[BM * BK], Bs[BN * BK];
    int lane = threadIdx.x & 63, wave = threadIdx.x >> 6;
    int wm = wave >> 1, wn = wave & 1;
    int m0 = blockIdx.x * BM;
    f32x4 acc[4][4] = {};
    for (int kt = 0; kt < 2; ++kt) {
        stage_tile(A + (size_t)m0 * 128 + kt * BK, 128, As, wave, lane);
        stage_tile(Bt + (size_t)kt * BK, 128, Bs, wave, lane);
        __syncthreads();
        mma_tile(As, Bs, wm, wn, lane, acc);
        __syncthreads();
    }
    int lm = lane & 15, lq = lane >> 4;
    #pragma unroll
    for (int tn = 0; tn < 4; ++tn) {
        int n = wn * 64 + tn * 16 + lm;
        float bn = bias[n];
        #pragma unroll
        for (int tm = 0; tm < 4; ++tm) {
            int mb = m0 + wm * 64 + tm * 16 + lq * 4;
            float4 pk;
            pk.x = acc[tm][tn][0] + bn;
            pk.y = acc[tm][tn][1] + bn;
            pk.z = acc[tm][tn][2] + bn;
            pk.w = acc[tm][tn][3] + bn;
            *(float4*)(out + (size_t)n * 25600 + mb) = pk;
        }
    }
}

// -------- norm+gelu with inline finalize (mean/rsqrt derived from raw sums) --------
__global__ void k_normgelu8f(const unsigned short* __restrict__ Y, const float* __restrict__ st,
                             unsigned short* __restrict__ X2, int Cmask, int C, float inv_n,
                             int total8) {
    int i8 = blockIdx.x * 256 + threadIdx.x;
    if (i8 >= total8) return;
    int e0 = i8 * 8;
    int c = e0 & Cmask;
    uint4 y = *(const uint4*)(Y + e0);
    float4 s1a = *(const float4*)(st + c);
    float4 s1b = *(const float4*)(st + c + 4);
    float4 s2a = *(const float4*)(st + C + c);
    float4 s2b = *(const float4*)(st + C + c + 4);
    float mu[8] = { s1a.x * inv_n, s1a.y * inv_n, s1a.z * inv_n, s1a.w * inv_n,
                    s1b.x * inv_n, s1b.y * inv_n, s1b.z * inv_n, s1b.w * inv_n };
    float sq[8] = { s2a.x, s2a.y, s2a.z, s2a.w, s2b.x, s2b.y, s2b.z, s2b.w };
    float rs[8];
    #pragma unroll
    for (int j = 0; j < 8; ++j) rs[j] = rsqrtf(sq[j] * inv_n - mu[j] * mu[j] + 1e-5f);
    const float is2 = 0.70710678118654752f;
    unsigned int yw[4] = {y.x, y.y, y.z, y.w};
    unsigned int ow[4];
    #pragma unroll
    for (int j = 0; j < 4; ++j) {
        float v0 = (b2f_bits((unsigned short)(yw[j] & 0xffffu)) - mu[j * 2]) * rs[j * 2];
        float v1 = (b2f_bits((unsigned short)(yw[j] >> 16)) - mu[j * 2 + 1]) * rs[j * 2 + 1];
        float g0 = 0.5f * v0 * (1.f + erff(v0 * is2));
        float g1 = 0.5f * v1 * (1.f + erff(v1 * is2));
        ow[j] = (uint32_t)f2b(g0) | ((uint32_t)f2b(g1) << 16);
    }
    *(uint4*)(X2 + e0) = make_uint4(ow[0], ow[1], ow[2], ow[3]);
}

// ---------------- launch ----------------
extern "C" void kernel_launch(void* const* d_in, const int* in_sizes, int n_in,
                              void* d_out, int out_size, void* d_ws, size_t ws_size,
                              hipStream_t stream) {
    (void)in_sizes; (void)n_in; (void)out_size; (void)ws_size;
    const float* feat = (const float*)d_in[0];
    const float* l2i  = (const float*)d_in[1];
    const float* bev  = (const float*)d_in[2];
    const float* pw1  = (const float*)d_in[3];
    const float* pb1  = (const float*)d_in[4];
    const float* pw2  = (const float*)d_in[5];
    const float* pb2  = (const float*)d_in[6];
    const float* pw3  = (const float*)d_in[7];
    const float* pb3  = (const float*)d_in[8];
    const float* c1w  = (const float*)d_in[9];
    const float* c1b  = (const float*)d_in[10];
    const float* c2w  = (const float*)d_in[11];
    const float* c2b  = (const float*)d_in[12];
    const float* c3w  = (const float*)d_in[13];
    const float* c3b  = (const float*)d_in[14];
    float* outp = (float*)d_out;
    char* ws = (char*)d_ws;

    // ---- workspace layout (bytes), peak ~148.6 MB ----
    unsigned short* featT = (unsigned short*)(ws + 0);          //  4,325,376 + 23,040 pad
    unsigned short* W2Tb  = (unsigned short*)(ws + 4348416);    //    131,072 [256][256] bf16 [o][k]
    unsigned short* W3Tb  = (unsigned short*)(ws + 4479488);    //     65,536 [128][256]
    unsigned short* C1Wb  = (unsigned short*)(ws + 4545024);    //    524,288 [512][512]
    unsigned short* C2Wb  = (unsigned short*)(ws + 5069312);    //    131,072 [128][512]
    unsigned short* C3Wb  = (unsigned short*)(ws + 5200384);    //     32,768 [128][128]
    float* stats          = (float*)(ws + 5233152);             //     10,240
    float* w1p            = (float*)(ws + 5243392);             //      4,096 [256][4]
    int*    poff          = (int*)(ws + 5247488);               //  2,457,600 [6][102400]
    float4* pwts          = (float4*)(ws + 7705088);            //  9,830,400 [6][102400]
    char* BUF1 = ws + 17535488;   // 52,428,800: X bf16 -> Y2 bf16 + X3 bf16
    char* BUF2 = ws + 69964288;   // 52,428,800: H2 bf16 -> Y1 bf16 (26 MB)
    char* BUF3 = ws + 122393088;  // 26,214,400: samp bf16 -> X2 bf16
    // total = 148,607,488

    float* st512 = stats;          // 1024 f (sums + sumsq)
    float* st128 = stats + 2048;   // 256 f

    unsigned short* H2   = (unsigned short*)BUF2;
    unsigned short* samp = (unsigned short*)BUF3;
    unsigned short* X    = (unsigned short*)BUF1;
    unsigned short* Y1   = (unsigned short*)BUF2;               // after H2 dead (conv1)
    unsigned short* X2   = (unsigned short*)BUF3;               // after samp dead (normgelu1)
    unsigned short* Y2   = (unsigned short*)BUF1;               // after X dead (conv2)
    unsigned short* X3   = (unsigned short*)(BUF1 + 6553600);

    hipMemsetAsync(stats, 0, 10240, stream);
    // merged prep: projection + all transposes/casts + w1 pack
    k_prep<<<12577, 256, 0, stream>>>(feat, pw2, pw3, c1w, c2w, c3w, pw1, pb1, l2i, bev,
                                      featT, W2Tb, W3Tb, C1Wb, C2Wb, C3Wb, w1p, poff, pwts);

    // gather-only sampling
    k_sample2<<<25600, 256, 0, stream>>>(featT, poff, pwts, samp);

    // PE MLP (pe1 fused into pe2 staging)
    k_gemm_pe2f<<<400, 1024, 0, stream>>>(bev, w1p, W2Tb, pb2, H2);
    k_gemm_pe3<<<dim3(800, 1), 256, 0, stream>>>(H2, W3Tb, pb3, samp, X);

    // conv1 (512->512) + fused stats, then norm+gelu (inline finalize)
    k_gemm_conv1_big<<<dim3(100, 2), 1024, 0, stream>>>(X, C1Wb, c1b, Y1, st512);
    k_normgelu8f<<<6400, 256, 0, stream>>>(Y1, st512, X2, 511, 512, 1.f / 25600.f, 1638400);

    // conv2 (512->128) + fused stats, then norm+gelu (inline finalize)
    k_gemm_conv<512, true><<<dim3(200, 1), 256, 0, stream>>>(X2, C2Wb, c2b, Y2, 128, st128, 128);
    k_normgelu8f<<<1600, 256, 0, stream>>>(Y2, st128, X3, 127, 128, 1.f / 25600.f, 409600);

    // conv3 (128->128) -> out f32 [128][25600]
    k_gemm_conv3<<<dim3(200, 1), 256, 0, stream>>>(X3, C3Wb, c3b, outp);
}

// Round 11
// 287.576 us; speedup vs baseline: 1.1289x; 1.1289x over previous
//
#include <hip/hip_runtime.h>
#include <cstdint>
#include <cstddef>

using frag8 = __attribute__((ext_vector_type(8))) short;   // 8 bf16
using f32x4 = __attribute__((ext_vector_type(4))) float;

__device__ __forceinline__ float b2f_bits(unsigned short u) {
    union { uint32_t u32; float f; } x; x.u32 = ((uint32_t)u) << 16; return x.f;
}
__device__ __forceinline__ float b2f_lo(uint32_t pk) {
    return __builtin_bit_cast(float, pk << 16);
}
__device__ __forceinline__ float b2f_hi(uint32_t pk) {
    return __builtin_bit_cast(float, pk & 0xffff0000u);
}
__device__ __forceinline__ unsigned short f2b(float f) {   // RNE f32 -> bf16
    uint32_t u = __builtin_bit_cast(uint32_t, f);
    uint32_t r = (u + 0x7fffu + ((u >> 16) & 1u)) >> 16;
    return (unsigned short)r;
}

#define HF 32
#define WFEAT 88
#define NCAM 6
#define NPT 102400
#define BM 128
#define BN 128
#define BK 64

// ================= merged prep: pe1 + project + transposes + casts + stats zero =============
// grid = 25600 (pe1) + 2400 (project) + 8448 (featT: 6*128*32*88 = 2,162,688 = 8448*256)
//        + 256 (w2T) + 128 (w3T) + 1024 + 256 + 64 (casts) + 1 (stats zero) = 38177
__global__ __launch_bounds__(256) void k_prep(const float* __restrict__ feat,
                                              const float* __restrict__ pw2,
                                              const float* __restrict__ pw3,
                                              const float* __restrict__ c1w,
                                              const float* __restrict__ c2w,
                                              const float* __restrict__ c3w,
                                              const float* __restrict__ pw1,
                                              const float* __restrict__ pb1,
                                              const float* __restrict__ l2i,
                                              const float* __restrict__ bev,
                                              unsigned short* __restrict__ featT,
                                              unsigned short* __restrict__ W2Tb,
                                              unsigned short* __restrict__ W3Tb,
                                              unsigned short* __restrict__ C1Wb,
                                              unsigned short* __restrict__ C2Wb,
                                              unsigned short* __restrict__ C3Wb,
                                              unsigned short* __restrict__ H1,
                                              float* __restrict__ stats,
                                              int* __restrict__ poff,
                                              float4* __restrict__ pwts) {
    int b = blockIdx.x, t = threadIdx.x;
    if (b < 25600) {                      // ---- pe1: H1 = relu(bev01 @ w1 + b1), 4 out/thread ----
        int idx = b * 256 + t;            // < 6,553,600
        int m = idx >> 6;
        int o4 = (idx & 63) * 4;
        int q = m >> 2, p = m & 3;
        int h = q / 160, w = q - h * 160;
        const float* bv = bev + ((p * 160 + h) * 160 + w) * 3;
        float cx = bv[0], cy = bv[1], cz = bv[2];
        float4 a0 = *(const float4*)(pw1 + o4);
        float4 a1 = *(const float4*)(pw1 + 256 + o4);
        float4 a2 = *(const float4*)(pw1 + 512 + o4);
        float4 bb = *(const float4*)(pb1 + o4);
        ushort4 o;
        o.x = f2b(fmaxf(cx * a0.x + cy * a1.x + cz * a2.x + bb.x, 0.f));
        o.y = f2b(fmaxf(cx * a0.y + cy * a1.y + cz * a2.y + bb.y, 0.f));
        o.z = f2b(fmaxf(cx * a0.z + cy * a1.z + cz * a2.z + bb.z, 0.f));
        o.w = f2b(fmaxf(cx * a0.w + cy * a1.w + cz * a2.w + bb.w, 0.f));
        *(ushort4*)(H1 + (size_t)m * 256 + o4) = o;
        return;
    }
    b -= 25600;
    if (b < 2400) {                       // ---- projection precompute (cam, point) ----
        int idx = b * 256 + t;            // n*NPT + pt, < 614400
        int n = idx / NPT, pt = idx - n * NPT;
        int q = pt >> 2, p = pt & 3;
        int h = q / 160, w = q - h * 160;
        const float* bv = bev + ((p * 160 + h) * 160 + w) * 3;
        float rx = bv[0] * 100.f - 50.f;
        float ry = bv[1] * 100.f - 50.f;
        float rz = bv[2] * 8.f - 4.f;
        const float* M = l2i + n * 16;
        float c0   = M[0] * rx + M[1] * ry + M[2]  * rz + M[3];
        float c1v  = M[4] * rx + M[5] * ry + M[6]  * rz + M[7];
        float homo = M[8] * rx + M[9] * ry + M[10] * rz + M[11];
        float z = fmaxf(homo, 1e-5f);
        float u = c0 / z / 704.0f;
        float v = c1v / z / 256.0f;
        if (!(homo > 1e-5f && u > 0.f && u < 1.f && v > 0.f && v < 1.f)) {
            poff[idx] = -1;
            return;
        }
        float fx = u * (float)WFEAT - 0.5f;
        float fy = v * (float)HF - 0.5f;
        float fx0 = floorf(fx), fy0 = floorf(fy);
        float dx = fx - fx0, dy = fy - fy0;
        int x0 = (int)fx0, y0 = (int)fy0;
        float wxa = (x0 < 0) ? dx : 1.f - dx;
        float wxb = (x0 >= 0 && x0 < WFEAT - 1) ? dx : 0.f;
        float wya = (y0 < 0) ? dy : 1.f - dy;
        float wyb = (y0 >= 0 && y0 < HF - 1) ? dy : 0.f;
        int bx = max(x0, 0), by = max(y0, 0);
        poff[idx] = ((n * HF + by) * WFEAT + bx) << 7;
        pwts[idx] = make_float4(wxa * wya, wxb * wya, wxa * wyb, wxb * wyb);
        return;
    }
    b -= 2400;
    if (b < 8448) {                       // ---- feat -> featT (channel-last bf16) ----
        int idx = b * 256 + t;            // < 2,162,688 exactly
        int c = idx & 127;
        int rest = idx >> 7;
        int x = rest % WFEAT; rest /= WFEAT;
        int y = rest % HF;
        int n = rest / HF;
        featT[idx] = f2b(feat[((n * 128 + c) * HF + y) * WFEAT + x]);
        return;
    }
    b -= 8448;
    if (b < 256) {                        // ---- pw2 [256][256] -> W2Tb [o][k] ----
        int idx = b * 256 + t;
        int r = idx >> 8, c = idx & 255;
        W2Tb[c * 256 + r] = f2b(pw2[idx]);
        return;
    }
    b -= 256;
    if (b < 128) {                        // ---- pw3 [256][128] -> W3Tb [o][k] ----
        int idx = b * 256 + t;
        int r = idx >> 7, c = idx & 127;
        W3Tb[c * 256 + r] = f2b(pw3[idx]);
        return;
    }
    b -= 128;
    if (b < 1024) { int idx = b * 256 + t; C1Wb[idx] = f2b(c1w[idx]); return; }
    b -= 1024;
    if (b < 256)  { int idx = b * 256 + t; C2Wb[idx] = f2b(c2w[idx]); return; }
    b -= 256;
    if (b < 64)   { int idx = b * 256 + t; C3Wb[idx] = f2b(c3w[idx]); return; }
    // ---- stats zero (2560 floats) ----
    #pragma unroll
    for (int j = 0; j < 10; ++j) stats[t * 10 + j] = 0.f;
}

// ---------------- gather-only sampling: one wave per point, lane = 2 channels ----------------
__global__ __launch_bounds__(256) void k_sample2(const unsigned short* __restrict__ featT,
                                                 const int* __restrict__ poff,
                                                 const float4* __restrict__ pwts,
                                                 unsigned short* __restrict__ samp) {
    int pt = blockIdx.x * 4 + (threadIdx.x >> 6);
    int lane = threadIdx.x & 63;
    int c2 = lane * 2;
    int offs[NCAM];
    float4 ww[NCAM];
    #pragma unroll
    for (int n = 0; n < NCAM; ++n) offs[n] = poff[n * NPT + pt];
    #pragma unroll
    for (int n = 0; n < NCAM; ++n) ww[n] = pwts[n * NPT + pt];   // garbage if invalid; unused
    float acc0 = 0.f, acc1 = 0.f;
    #pragma unroll
    for (int n = 0; n < NCAM; ++n) {
        if (offs[n] >= 0) {                        // wave-uniform scalar branch
            const unsigned short* base = featT + offs[n] + c2;
            uint32_t p00 = *(const uint32_t*)(base);
            uint32_t p01 = *(const uint32_t*)(base + 128);
            uint32_t p10 = *(const uint32_t*)(base + WFEAT * 128);
            uint32_t p11 = *(const uint32_t*)(base + WFEAT * 128 + 128);
            float4 w = ww[n];
            acc0 += w.x * b2f_lo(p00) + w.y * b2f_lo(p01) + w.z * b2f_lo(p10) + w.w * b2f_lo(p11);
            acc1 += w.x * b2f_hi(p00) + w.y * b2f_hi(p01) + w.z * b2f_hi(p10) + w.w * b2f_hi(p11);
        }
    }
    uint32_t outpk = (uint32_t)f2b(acc0) | ((uint32_t)f2b(acc1) << 16);
    *(uint32_t*)(samp + (size_t)pt * 128 + c2) = outpk;
}

// ================= 1024-thread (16-wave) GEMM: 256x256 tile, BK=32, dbuf =================
// LDS tile 256 rows x 32 cols bf16 = 16 KB; chunk = 8 bf16 = 16 B; slot = chunk ^ ((row>>1)&3)
__device__ __forceinline__ void stage_tile_big(const unsigned short* __restrict__ g, int ld,
                                               unsigned short* lds, int t) {
    int r = t >> 2, cs = t & 3;
    int cl = cs ^ ((r >> 1) & 3);                  // logical chunk held by slot (r,cs)
    __builtin_amdgcn_global_load_lds(
        (const __attribute__((address_space(1))) void*)(g + (size_t)r * ld + cl * 8),
        (__attribute__((address_space(3))) void*)(lds + (t >> 6) * 512),   // wave-uniform base
        16, 0, 0);
}

__device__ __forceinline__ frag8 frag_read_big(const unsigned short* lds, int row, int chunk) {
    return *(const frag8*)(lds + row * 32 + ((chunk ^ ((row >> 1) & 3)) << 3));
}

__device__ __forceinline__ void mma_tile_big(const unsigned short* As, const unsigned short* Bs,
                                             int wm, int wn, int lane, f32x4 (&acc)[4][4]) {
    int lm = lane & 15, lq = lane >> 4;            // lq = k-chunk 0..3
    frag8 a[4], b[4];
    #pragma unroll
    for (int t = 0; t < 4; ++t) a[t] = frag_read_big(As, wm * 64 + t * 16 + lm, lq);
    #pragma unroll
    for (int t = 0; t < 4; ++t) b[t] = frag_read_big(Bs, wn * 64 + t * 16 + lm, lq);
    #pragma unroll
    for (int tm = 0; tm < 4; ++tm)
        #pragma unroll
        for (int tn = 0; tn < 4; ++tn)
            acc[tm][tn] = __builtin_amdgcn_mfma_f32_16x16x32_bf16(a[tm], b[tn], acc[tm][tn], 0, 0, 0);
}

template <int KT>
__device__ __forceinline__ void gemm_loop_big(const unsigned short* __restrict__ A, int ldA,
                                              const unsigned short* __restrict__ B, int ldB,
                                              unsigned short (*As)[256 * 32],
                                              unsigned short (*Bs)[256 * 32],
                                              int t, int wm, int wn, int lane,
                                              f32x4 (&acc)[4][4]) {
    stage_tile_big(A, ldA, As[0], t);
    stage_tile_big(B, ldB, Bs[0], t);
    __syncthreads();
    #pragma unroll
    for (int kt = 0; kt < KT; ++kt) {
        int cur = kt & 1, nxt = cur ^ 1;
        if (kt + 1 < KT) {                         // prefetch flies during mma
            stage_tile_big(A + (kt + 1) * 32, ldA, As[nxt], t);
            stage_tile_big(B + (kt + 1) * 32, ldB, Bs[nxt], t);
        }
        mma_tile_big(As[cur], Bs[cur], wm, wn, lane, acc);
        __syncthreads();
    }
}

// pe2 big: H2 = relu(H1 @ W2T^T + b2), M=102400, N=256, K=256 -> grid(400), 1024 thr
__global__ __launch_bounds__(1024) void k_gemm_pe2_big(const unsigned short* __restrict__ A,
                                                       const unsigned short* __restrict__ Bt,
                                                       const float* __restrict__ bias,
                                                       unsigned short* __restrict__ H2) {
    __shared__ unsigned short As[2][256 * 32], Bs[2][256 * 32];
    int t = threadIdx.x, lane = t & 63, wid = t >> 6;
    int wm = wid >> 2, wn = wid & 3;
    int m0 = blockIdx.x * 256;
    f32x4 acc[4][4] = {};
    gemm_loop_big<8>(A + (size_t)m0 * 256, 256, Bt, 256, As, Bs, t, wm, wn, lane, acc);
    int lm = lane & 15, lq = lane >> 4;
    #pragma unroll
    for (int tn = 0; tn < 4; ++tn) {
        int n = wn * 64 + tn * 16 + lm;
        float bn = bias[n];
        #pragma unroll
        for (int tm = 0; tm < 4; ++tm) {
            int mb = m0 + wm * 64 + tm * 16 + lq * 4;
            #pragma unroll
            for (int rr = 0; rr < 4; ++rr)
                H2[(size_t)(mb + rr) * 256 + n] = f2b(fmaxf(acc[tm][tn][rr] + bn, 0.f));
        }
    }
}

// conv1 big: Y1 = X @ C1W^T + b, M=25600, N=512, K=512 -> grid(100,2), 1024 thr, fused stats
__global__ __launch_bounds__(1024) void k_gemm_conv1_big(const unsigned short* __restrict__ A,
                                                         const unsigned short* __restrict__ Bt,
                                                         const float* __restrict__ bias,
                                                         unsigned short* __restrict__ Y,
                                                         float* __restrict__ st) {
    __shared__ unsigned short As[2][256 * 32], Bs[2][256 * 32];
    int t = threadIdx.x, lane = t & 63, wid = t >> 6;
    int wm = wid >> 2, wn = wid & 3;
    int m0 = blockIdx.x * 256, n0 = blockIdx.y * 256;
    f32x4 acc[4][4] = {};
    gemm_loop_big<16>(A + (size_t)m0 * 512, 512, Bt + (size_t)n0 * 512, 512,
                      As, Bs, t, wm, wn, lane, acc);
    int lm = lane & 15, lq = lane >> 4;
    #pragma unroll
    for (int tn = 0; tn < 4; ++tn) {
        int n = n0 + wn * 64 + tn * 16 + lm;
        float bn = bias[n];
        float s1 = 0.f, s2 = 0.f;
        #pragma unroll
        for (int tm = 0; tm < 4; ++tm) {
            int mb = m0 + wm * 64 + tm * 16 + lq * 4;
            #pragma unroll
            for (int rr = 0; rr < 4; ++rr) {
                float v = acc[tm][tn][rr] + bn;
                Y[(size_t)(mb + rr) * 512 + n] = f2b(v);
                s1 += v; s2 += v * v;
            }
        }
        s1 += __shfl_xor(s1, 16); s1 += __shfl_xor(s1, 32);
        s2 += __shfl_xor(s2, 16); s2 += __shfl_xor(s2, 32);
        if (lq == 0) { atomicAdd(&st[n], s1); atomicAdd(&st[512 + n], s2); }
    }
}

// ================= 256-thread GEMM (single-buffer) =================
__device__ __forceinline__ void stage_tile(const unsigned short* __restrict__ g, int ld,
                                           unsigned short* lds, int wave, int lane) {
    #pragma unroll
    for (int j = 0; j < 4; ++j) {
        int idx = wave * 256 + j * 64 + lane;      // chunk slot index 0..1023
        int r = idx >> 3;
        int cs = idx & 7;
        int cl = cs ^ (r & 7);                     // logical chunk this slot holds
        __builtin_amdgcn_global_load_lds(
            (const __attribute__((address_space(1))) void*)(g + (size_t)r * ld + cl * 8),
            (__attribute__((address_space(3))) void*)(lds + wave * 2048 + j * 512),
            16, 0, 0);
    }
}

__device__ __forceinline__ frag8 frag_read(const unsigned short* lds, int row, int chunk) {
    return *(const frag8*)(lds + row * 64 + ((chunk ^ (row & 7)) << 3));
}

__device__ __forceinline__ void mma_tile(const unsigned short* As, const unsigned short* Bs,
                                         int wm, int wn, int lane, f32x4 (&acc)[4][4]) {
    int lm = lane & 15, lq = lane >> 4;
    #pragma unroll
    for (int kk = 0; kk < 2; ++kk) {
        frag8 a[4], b[4];
        #pragma unroll
        for (int t = 0; t < 4; ++t) a[t] = frag_read(As, wm * 64 + t * 16 + lm, kk * 4 + lq);
        #pragma unroll
        for (int t = 0; t < 4; ++t) b[t] = frag_read(Bs, wn * 64 + t * 16 + lm, kk * 4 + lq);
        #pragma unroll
        for (int tm = 0; tm < 4; ++tm)
            #pragma unroll
            for (int tn = 0; tn < 4; ++tn)
                acc[tm][tn] = __builtin_amdgcn_mfma_f32_16x16x32_bf16(a[tm], b[tn], acc[tm][tn], 0, 0, 0);
    }
}

// ---------------- pe3: X = bf16(samp + H2 @ W3T^T + b3) ----------------
__global__ __launch_bounds__(256) void k_gemm_pe3(const unsigned short* __restrict__ A,
                                                  const unsigned short* __restrict__ Bt,
                                                  const float* __restrict__ bias,
                                                  const unsigned short* __restrict__ samp,
                                                  unsigned short* __restrict__ X) {
    __shared__ unsigned short As[BM * BK], Bs[BN * BK];
    int lane = threadIdx.x & 63, wave = threadIdx.x >> 6;
    int wm = wave >> 1, wn = wave & 1;
    int m0 = blockIdx.x * BM;
    f32x4 acc[4][4] = {};
    for (int kt = 0; kt < 4; ++kt) {
        stage_tile(A + (size_t)m0 * 256 + kt * BK, 256, As, wave, lane);
        stage_tile(Bt + (size_t)kt * BK, 256, Bs, wave, lane);
        __syncthreads();
        mma_tile(As, Bs, wm, wn, lane, acc);
        __syncthreads();
    }
    int lm = lane & 15, lq = lane >> 4;
    #pragma unroll
    for (int tn = 0; tn < 4; ++tn) {
        int n = wn * 64 + tn * 16 + lm;
        float bn = bias[n];
        #pragma unroll
        for (int tm = 0; tm < 4; ++tm) {
            int mb = m0 + wm * 64 + tm * 16 + lq * 4;
            #pragma unroll
            for (int rr = 0; rr < 4; ++rr) {
                size_t off = (size_t)(mb + rr) * 128 + n;
                X[off] = f2b(acc[tm][tn][rr] + bn + b2f_bits(samp[off]));
            }
        }
    }
}

// ---------------- conv2 GEMM -> bf16 Y + f32 inorm stats ----------------
template <int K, bool STATS>
__global__ __launch_bounds__(256) void k_gemm_conv(const unsigned short* __restrict__ A,
                                                   const unsigned short* __restrict__ Bt,
                                                   const float* __restrict__ bias,
                                                   unsigned short* __restrict__ Y, int ldY,
                                                   float* __restrict__ st, int C) {
    __shared__ unsigned short As[BM * BK], Bs[BN * BK];
    int lane = threadIdx.x & 63, wave = threadIdx.x >> 6;
    int wm = wave >> 1, wn = wave & 1;
    int m0 = blockIdx.x * BM, n0 = blockIdx.y * BN;
    f32x4 acc[4][4] = {};
    for (int kt = 0; kt < K / BK; ++kt) {
        stage_tile(A + (size_t)m0 * K + kt * BK, K, As, wave, lane);
        stage_tile(Bt + (size_t)n0 * K + kt * BK, K, Bs, wave, lane);
        __syncthreads();
        mma_tile(As, Bs, wm, wn, lane, acc);
        __syncthreads();
    }
    int lm = lane & 15, lq = lane >> 4;
    #pragma unroll
    for (int tn = 0; tn < 4; ++tn) {
        int n = n0 + wn * 64 + tn * 16 + lm;
        float bn = bias[n];
        float s1 = 0.f, s2 = 0.f;
        #pragma unroll
        for (int tm = 0; tm < 4; ++tm) {
            int mb = m0 + wm * 64 + tm * 16 + lq * 4;
            #pragma unroll
            for (int rr = 0; rr < 4; ++rr) {
                float v = acc[tm][tn][rr] + bn;
                Y[(size_t)(mb + rr) * ldY + n] = f2b(v);
                if (STATS) { s1 += v; s2 += v * v; }
            }
        }
        if (STATS) {
            s1 += __shfl_xor(s1, 16); s1 += __shfl_xor(s1, 32);
            s2 += __shfl_xor(s2, 16); s2 += __shfl_xor(s2, 32);
            if (lq == 0) { atomicAdd(&st[n], s1); atomicAdd(&st[C + n], s2); }
        }
    }
}

// ---------------- conv3 -> out f32 [128][25600] ----------------
__global__ __launch_bounds__(256) void k_gemm_conv3(const unsigned short* __restrict__ A,
                                                    const unsigned short* __restrict__ Bt,
                                                    const float* __restrict__ bias,
                                                    float* __restrict__ out) {
    __shared__ unsigned short As[BM * BK], Bs[BN * BK];
    int lane = threadIdx.x & 63, wave = threadIdx.x >> 6;
    int wm = wave >> 1, wn = wave & 1;
    int m0 = blockIdx.x * BM;
    f32x4 acc[4][4] = {};
    for (int kt = 0; kt < 2; ++kt) {
        stage_tile(A + (size_t)m0 * 128 + kt * BK, 128, As, wave, lane);
        stage_tile(Bt + (size_t)kt * BK, 128, Bs, wave, lane);
        __syncthreads();
        mma_tile(As, Bs, wm, wn, lane, acc);
        __syncthreads();
    }
    int lm = lane & 15, lq = lane >> 4;
    #pragma unroll
    for (int tn = 0; tn < 4; ++tn) {
        int n = wn * 64 + tn * 16 + lm;
        float bn = bias[n];
        #pragma unroll
        for (int tm = 0; tm < 4; ++tm) {
            int mb = m0 + wm * 64 + tm * 16 + lq * 4;
            float4 pk;
            pk.x = acc[tm][tn][0] + bn;
            pk.y = acc[tm][tn][1] + bn;
            pk.z = acc[tm][tn][2] + bn;
            pk.w = acc[tm][tn][3] + bn;
            *(float4*)(out + (size_t)n * 25600 + mb) = pk;
        }
    }
}

// -------- norm+gelu with inline finalize (mean/rsqrt derived from raw sums) --------
__global__ void k_normgelu8f(const unsigned short* __restrict__ Y, const float* __restrict__ st,
                             unsigned short* __restrict__ X2, int Cmask, int C, float inv_n,
                             int total8) {
    int i8 = blockIdx.x * 256 + threadIdx.x;
    if (i8 >= total8) return;
    int e0 = i8 * 8;
    int c = e0 & Cmask;
    uint4 y = *(const uint4*)(Y + e0);
    float4 s1a = *(const float4*)(st + c);
    float4 s1b = *(const float4*)(st + c + 4);
    float4 s2a = *(const float4*)(st + C + c);
    float4 s2b = *(const float4*)(st + C + c + 4);
    float mu[8] = { s1a.x * inv_n, s1a.y * inv_n, s1a.z * inv_n, s1a.w * inv_n,
                    s1b.x * inv_n, s1b.y * inv_n, s1b.z * inv_n, s1b.w * inv_n };
    float sq[8] = { s2a.x, s2a.y, s2a.z, s2a.w, s2b.x, s2b.y, s2b.z, s2b.w };
    float rs[8];
    #pragma unroll
    for (int j = 0; j < 8; ++j) rs[j] = rsqrtf(sq[j] * inv_n - mu[j] * mu[j] + 1e-5f);
    const float is2 = 0.70710678118654752f;
    unsigned int yw[4] = {y.x, y.y, y.z, y.w};
    unsigned int ow[4];
    #pragma unroll
    for (int j = 0; j < 4; ++j) {
        float v0 = (b2f_bits((unsigned short)(yw[j] & 0xffffu)) - mu[j * 2]) * rs[j * 2];
        float v1 = (b2f_bits((unsigned short)(yw[j] >> 16)) - mu[j * 2 + 1]) * rs[j * 2 + 1];
        float g0 = 0.5f * v0 * (1.f + erff(v0 * is2));
        float g1 = 0.5f * v1 * (1.f + erff(v1 * is2));
        ow[j] = (uint32_t)f2b(g0) | ((uint32_t)f2b(g1) << 16);
    }
    *(uint4*)(X2 + e0) = make_uint4(ow[0], ow[1], ow[2], ow[3]);
}

// ---------------- launch ----------------
extern "C" void kernel_launch(void* const* d_in, const int* in_sizes, int n_in,
                              void* d_out, int out_size, void* d_ws, size_t ws_size,
                              hipStream_t stream) {
    (void)in_sizes; (void)n_in; (void)out_size; (void)ws_size;
    const float* feat = (const float*)d_in[0];
    const float* l2i  = (const float*)d_in[1];
    const float* bev  = (const float*)d_in[2];
    const float* pw1  = (const float*)d_in[3];
    const float* pb1  = (const float*)d_in[4];
    const float* pw2  = (const float*)d_in[5];
    const float* pb2  = (const float*)d_in[6];
    const float* pw3  = (const float*)d_in[7];
    const float* pb3  = (const float*)d_in[8];
    const float* c1w  = (const float*)d_in[9];
    const float* c1b  = (const float*)d_in[10];
    const float* c2w  = (const float*)d_in[11];
    const float* c2b  = (const float*)d_in[12];
    const float* c3w  = (const float*)d_in[13];
    const float* c3b  = (const float*)d_in[14];
    float* outp = (float*)d_out;
    char* ws = (char*)d_ws;

    // ---- workspace layout (bytes), peak ~148.6 MB ----
    unsigned short* featT = (unsigned short*)(ws + 0);          //  4,325,376 + 23,040 pad
    unsigned short* W2Tb  = (unsigned short*)(ws + 4348416);    //    131,072 [256][256] bf16 [o][k]
    unsigned short* W3Tb  = (unsigned short*)(ws + 4479488);    //     65,536 [128][256]
    unsigned short* C1Wb  = (unsigned short*)(ws + 4545024);    //    524,288 [512][512]
    unsigned short* C2Wb  = (unsigned short*)(ws + 5069312);    //    131,072 [128][512]
    unsigned short* C3Wb  = (unsigned short*)(ws + 5200384);    //     32,768 [128][128]
    float* stats          = (float*)(ws + 5233152);             //     10,240
    int*    poff          = (int*)(ws + 5247488);               //  2,457,600 [6][102400]
    float4* pwts          = (float4*)(ws + 7705088);            //  9,830,400 [6][102400]
    char* BUF1 = ws + 17535488;   // 52,428,800: H1 bf16 -> X bf16 -> Y2 bf16 + X3 bf16
    char* BUF2 = ws + 69964288;   // 52,428,800: H2 bf16 -> Y1 bf16 (26 MB)
    char* BUF3 = ws + 122393088;  // 26,214,400: samp bf16 -> X2 bf16
    // total = 148,607,488

    float* st512 = stats;          // 1024 f (sums + sumsq)
    float* st128 = stats + 2048;   // 256 f

    unsigned short* H1   = (unsigned short*)BUF1;
    unsigned short* H2   = (unsigned short*)BUF2;
    unsigned short* samp = (unsigned short*)BUF3;
    unsigned short* X    = (unsigned short*)BUF1;               // after H1 dead (pe3)
    unsigned short* Y1   = (unsigned short*)BUF2;               // after H2 dead (conv1)
    unsigned short* X2   = (unsigned short*)BUF3;               // after samp dead (normgelu1)
    unsigned short* Y2   = (unsigned short*)BUF1;               // after X dead (conv2)
    unsigned short* X3   = (unsigned short*)(BUF1 + 6553600);

    // merged prep: pe1 + projection + transposes/casts + stats zero (no separate memset)
    k_prep<<<38177, 256, 0, stream>>>(feat, pw2, pw3, c1w, c2w, c3w, pw1, pb1, l2i, bev,
                                      featT, W2Tb, W3Tb, C1Wb, C2Wb, C3Wb, H1, stats,
                                      poff, pwts);

    // gather-only sampling
    k_sample2<<<25600, 256, 0, stream>>>(featT, poff, pwts, samp);

    // PE MLP
    k_gemm_pe2_big<<<400, 1024, 0, stream>>>(H1, W2Tb, pb2, H2);
    k_gemm_pe3<<<dim3(800, 1), 256, 0, stream>>>(H2, W3Tb, pb3, samp, X);

    // conv1 (512->512) + fused stats, then norm+gelu (inline finalize)
    k_gemm_conv1_big<<<dim3(100, 2), 1024, 0, stream>>>(X, C1Wb, c1b, Y1, st512);
    k_normgelu8f<<<6400, 256, 0, stream>>>(Y1, st512, X2, 511, 512, 1.f / 25600.f, 1638400);

    // conv2 (512->128) + fused stats, then norm+gelu (inline finalize)
    k_gemm_conv<512, true><<<dim3(200, 1), 256, 0, stream>>>(X2, C2Wb, c2b, Y2, 128, st128, 128);
    k_normgelu8f<<<1600, 256, 0, stream>>>(Y2, st128, X3, 127, 128, 1.f / 25600.f, 409600);

    // conv3 (128->128) -> out f32 [128][25600]
    k_gemm_conv3<<<dim3(200, 1), 256, 0, stream>>>(X3, C3Wb, c3b, outp);
}

// Round 13
// 280.243 us; speedup vs baseline: 1.1584x; 1.0262x over previous
//
#include <hip/hip_runtime.h>
#include <cstdint>
#include <cstddef>

using frag8 = __attribute__((ext_vector_type(8))) short;   // 8 bf16
using f32x4 = __attribute__((ext_vector_type(4))) float;

__device__ __forceinline__ float b2f_bits(unsigned short u) {
    union { uint32_t u32; float f; } x; x.u32 = ((uint32_t)u) << 16; return x.f;
}
__device__ __forceinline__ float b2f_lo(uint32_t pk) {
    return __builtin_bit_cast(float, pk << 16);
}
__device__ __forceinline__ float b2f_hi(uint32_t pk) {
    return __builtin_bit_cast(float, pk & 0xffff0000u);
}
__device__ __forceinline__ unsigned short f2b(float f) {   // RNE f32 -> bf16
    uint32_t u = __builtin_bit_cast(uint32_t, f);
    uint32_t r = (u + 0x7fffu + ((u >> 16) & 1u)) >> 16;
    return (unsigned short)r;
}

#define HF 32
#define WFEAT 88
#define NCAM 6
#define NPT 102400
#define BM 128
#define BN 128
#define BK 64

// ================= merged prep: pe1 + project + featT(LDS transpose) + casts + stats ========
// grid = 25600 (pe1) + 2400 (project) + 264 (featT tiles) + 256 (w2T) + 128 (w3T)
//        + 1024 + 256 + 64 (casts) + 1 (stats zero) = 29993
__global__ __launch_bounds__(256) void k_prep(const float* __restrict__ feat,
                                              const float* __restrict__ pw2,
                                              const float* __restrict__ pw3,
                                              const float* __restrict__ c1w,
                                              const float* __restrict__ c2w,
                                              const float* __restrict__ c3w,
                                              const float* __restrict__ pw1,
                                              const float* __restrict__ pb1,
                                              const float* __restrict__ l2i,
                                              const float* __restrict__ bev,
                                              unsigned short* __restrict__ featT,
                                              unsigned short* __restrict__ W2Tb,
                                              unsigned short* __restrict__ W3Tb,
                                              unsigned short* __restrict__ C1Wb,
                                              unsigned short* __restrict__ C2Wb,
                                              unsigned short* __restrict__ C3Wb,
                                              unsigned short* __restrict__ H1,
                                              float* __restrict__ stats,
                                              int* __restrict__ poff,
                                              float4* __restrict__ pwts) {
    __shared__ unsigned short tile[64 * 132];   // transpose tile (132 = 128 + pad)
    int b = blockIdx.x, t = threadIdx.x;
    if (b < 25600) {                      // ---- pe1: H1 = relu(bev01 @ w1 + b1), 4 out/thread ----
        int idx = b * 256 + t;            // < 6,553,600
        int m = idx >> 6;
        int o4 = (idx & 63) * 4;
        int q = m >> 2, p = m & 3;
        int h = q / 160, w = q - h * 160;
        const float* bv = bev + ((p * 160 + h) * 160 + w) * 3;
        float cx = bv[0], cy = bv[1], cz = bv[2];
        float4 a0 = *(const float4*)(pw1 + o4);
        float4 a1 = *(const float4*)(pw1 + 256 + o4);
        float4 a2 = *(const float4*)(pw1 + 512 + o4);
        float4 bb = *(const float4*)(pb1 + o4);
        ushort4 o;
        o.x = f2b(fmaxf(cx * a0.x + cy * a1.x + cz * a2.x + bb.x, 0.f));
        o.y = f2b(fmaxf(cx * a0.y + cy * a1.y + cz * a2.y + bb.y, 0.f));
        o.z = f2b(fmaxf(cx * a0.z + cy * a1.z + cz * a2.z + bb.z, 0.f));
        o.w = f2b(fmaxf(cx * a0.w + cy * a1.w + cz * a2.w + bb.w, 0.f));
        *(ushort4*)(H1 + (size_t)m * 256 + o4) = o;
        return;
    }
    b -= 25600;
    if (b < 2400) {                       // ---- projection precompute (cam, point) ----
        int idx = b * 256 + t;            // n*NPT + pt, < 614400
        int n = idx / NPT, pt = idx - n * NPT;
        int q = pt >> 2, p = pt & 3;
        int h = q / 160, w = q - h * 160;
        const float* bv = bev + ((p * 160 + h) * 160 + w) * 3;
        float rx = bv[0] * 100.f - 50.f;
        float ry = bv[1] * 100.f - 50.f;
        float rz = bv[2] * 8.f - 4.f;
        const float* M = l2i + n * 16;
        float c0   = M[0] * rx + M[1] * ry + M[2]  * rz + M[3];
        float c1v  = M[4] * rx + M[5] * ry + M[6]  * rz + M[7];
        float homo = M[8] * rx + M[9] * ry + M[10] * rz + M[11];
        float z = fmaxf(homo, 1e-5f);
        float u = c0 / z / 704.0f;
        float v = c1v / z / 256.0f;
        if (!(homo > 1e-5f && u > 0.f && u < 1.f && v > 0.f && v < 1.f)) {
            poff[idx] = -1;
            return;
        }
        float fx = u * (float)WFEAT - 0.5f;
        float fy = v * (float)HF - 0.5f;
        float fx0 = floorf(fx), fy0 = floorf(fy);
        float dx = fx - fx0, dy = fy - fy0;
        int x0 = (int)fx0, y0 = (int)fy0;
        float wxa = (x0 < 0) ? dx : 1.f - dx;
        float wxb = (x0 >= 0 && x0 < WFEAT - 1) ? dx : 0.f;
        float wya = (y0 < 0) ? dy : 1.f - dy;
        float wyb = (y0 >= 0 && y0 < HF - 1) ? dy : 0.f;
        int bx = max(x0, 0), by = max(y0, 0);
        poff[idx] = ((n * HF + by) * WFEAT + bx) << 7;
        pwts[idx] = make_float4(wxa * wya, wxb * wya, wxa * wyb, wxb * wyb);
        return;
    }
    b -= 2400;
    if (b < 264) {                        // ---- feat -> featT via LDS tiled transpose ----
        // tile = 64 spatial (s = y*88+x, 2816/cam) x 128 channels
        int n = b / 44;
        int s0 = (b - n * 44) * 64;
        #pragma unroll
        for (int i = 0; i < 32; ++i) {
            int e = i * 256 + t;          // 8192 elems: c = e>>6, sl = e&63
            int c = e >> 6, sl = e & 63;
            tile[sl * 132 + c] = f2b(feat[(size_t)(n * 128 + c) * 2816 + s0 + sl]);
        }
        __syncthreads();
        #pragma unroll
        for (int j = 0; j < 8; ++j) {
            int flat = j * 1024 + t * 4;  // ushort4 chunks
            int sl = flat >> 7, c = flat & 127;
            ushort4 v = *(const ushort4*)(tile + sl * 132 + c);
            *(ushort4*)(featT + (size_t)(n * 2816 + s0 + sl) * 128 + c) = v;
        }
        return;
    }
    b -= 264;
    if (b < 256) {                        // ---- pw2 [256][256] -> W2Tb [o][k] ----
        int idx = b * 256 + t;
        int r = idx >> 8, c = idx & 255;
        W2Tb[c * 256 + r] = f2b(pw2[idx]);
        return;
    }
    b -= 256;
    if (b < 128) {                        // ---- pw3 [256][128] -> W3Tb [o][k] ----
        int idx = b * 256 + t;
        int r = idx >> 7, c = idx & 127;
        W3Tb[c * 128 + 0] = W3Tb[c * 128];  // no-op placeholder avoided; real write below
        W3Tb[c * 256 + r] = f2b(pw3[idx]);
        return;
    }
    b -= 128;
    if (b < 1024) { int idx = b * 256 + t; C1Wb[idx] = f2b(c1w[idx]); return; }
    b -= 1024;
    if (b < 256)  { int idx = b * 256 + t; C2Wb[idx] = f2b(c2w[idx]); return; }
    b -= 256;
    if (b < 64)   { int idx = b * 256 + t; C3Wb[idx] = f2b(c3w[idx]); return; }
    // ---- stats zero (2560 floats) ----
    #pragma unroll
    for (int j = 0; j < 10; ++j) stats[t * 10 + j] = 0.f;
}

// ---------------- gather-only sampling: one wave per point, lane = 2 channels ----------------
__global__ __launch_bounds__(256) void k_sample2(const unsigned short* __restrict__ featT,
                                                 const int* __restrict__ poff,
                                                 const float4* __restrict__ pwts,
                                                 unsigned short* __restrict__ samp) {
    int pt = blockIdx.x * 4 + (threadIdx.x >> 6);
    int lane = threadIdx.x & 63;
    int c2 = lane * 2;
    int offs[NCAM];
    float4 ww[NCAM];
    #pragma unroll
    for (int n = 0; n < NCAM; ++n) offs[n] = poff[n * NPT + pt];
    #pragma unroll
    for (int n = 0; n < NCAM; ++n) ww[n] = pwts[n * NPT + pt];   // garbage if invalid; unused
    float acc0 = 0.f, acc1 = 0.f;
    #pragma unroll
    for (int n = 0; n < NCAM; ++n) {
        if (offs[n] >= 0) {                        // wave-uniform scalar branch
            const unsigned short* base = featT + offs[n] + c2;
            uint32_t p00 = *(const uint32_t*)(base);
            uint32_t p01 = *(const uint32_t*)(base + 128);
            uint32_t p10 = *(const uint32_t*)(base + WFEAT * 128);
            uint32_t p11 = *(const uint32_t*)(base + WFEAT * 128 + 128);
            float4 w = ww[n];
            acc0 += w.x * b2f_lo(p00) + w.y * b2f_lo(p01) + w.z * b2f_lo(p10) + w.w * b2f_lo(p11);
            acc1 += w.x * b2f_hi(p00) + w.y * b2f_hi(p01) + w.z * b2f_hi(p10) + w.w * b2f_hi(p11);
        }
    }
    uint32_t outpk = (uint32_t)f2b(acc0) | ((uint32_t)f2b(acc1) << 16);
    *(uint32_t*)(samp + (size_t)pt * 128 + c2) = outpk;
}

// ================= 1024-thread (16-wave) GEMM: 256x256 tile, BK=32, dbuf =================
// (r8/r11-validated: ALL threads stage BOTH tiles — no split staging)
__device__ __forceinline__ void stage_tile_big(const unsigned short* __restrict__ g, int ld,
                                               unsigned short* lds, int t) {
    int r = t >> 2, cs = t & 3;
    int cl = cs ^ ((r >> 1) & 3);                  // logical chunk held by slot (r,cs)
    __builtin_amdgcn_global_load_lds(
        (const __attribute__((address_space(1))) void*)(g + (size_t)r * ld + cl * 8),
        (__attribute__((address_space(3))) void*)(lds + (t >> 6) * 512),   // wave-uniform base
        16, 0, 0);
}

__device__ __forceinline__ frag8 frag_read_big(const unsigned short* lds, int row, int chunk) {
    return *(const frag8*)(lds + row * 32 + ((chunk ^ ((row >> 1) & 3)) << 3));
}

__device__ __forceinline__ void mma_tile_big(const unsigned short* As, const unsigned short* Bs,
                                             int wm, int wn, int lane, f32x4 (&acc)[4][4]) {
    int lm = lane & 15, lq = lane >> 4;            // lq = k-chunk 0..3
    frag8 a[4], b[4];
    #pragma unroll
    for (int t = 0; t < 4; ++t) a[t] = frag_read_big(As, wm * 64 + t * 16 + lm, lq);
    #pragma unroll
    for (int t = 0; t < 4; ++t) b[t] = frag_read_big(Bs, wn * 64 + t * 16 + lm, lq);
    #pragma unroll
    for (int tm = 0; tm < 4; ++tm)
        #pragma unroll
        for (int tn = 0; tn < 4; ++tn)
            acc[tm][tn] = __builtin_amdgcn_mfma_f32_16x16x32_bf16(a[tm], b[tn], acc[tm][tn], 0, 0, 0);
}

template <int KT>
__device__ __forceinline__ void gemm_loop_big(const unsigned short* __restrict__ A, int ldA,
                                              const unsigned short* __restrict__ B, int ldB,
                                              unsigned short (*As)[256 * 32],
                                              unsigned short (*Bs)[256 * 32],
                                              int t, int wm, int wn, int lane,
                                              f32x4 (&acc)[4][4]) {
    stage_tile_big(A, ldA, As[0], t);
    stage_tile_big(B, ldB, Bs[0], t);
    __syncthreads();
    #pragma unroll
    for (int kt = 0; kt < KT; ++kt) {
        int cur = kt & 1, nxt = cur ^ 1;
        if (kt + 1 < KT) {                         // prefetch flies during mma
            stage_tile_big(A + (kt + 1) * 32, ldA, As[nxt], t);
            stage_tile_big(B + (kt + 1) * 32, ldB, Bs[nxt], t);
        }
        mma_tile_big(As[cur], Bs[cur], wm, wn, lane, acc);
        __syncthreads();
    }
}

// pe2 big: H2 = relu(H1 @ W2T^T + b2), M=102400, N=256, K=256 -> grid(400), 1024 thr
__global__ __launch_bounds__(1024) void k_gemm_pe2_big(const unsigned short* __restrict__ A,
                                                       const unsigned short* __restrict__ Bt,
                                                       const float* __restrict__ bias,
                                                       unsigned short* __restrict__ H2) {
    __shared__ unsigned short As[2][256 * 32], Bs[2][256 * 32];
    int t = threadIdx.x, lane = t & 63, wid = t >> 6;
    int wm = wid >> 2, wn = wid & 3;
    int m0 = blockIdx.x * 256;
    f32x4 acc[4][4] = {};
    gemm_loop_big<8>(A + (size_t)m0 * 256, 256, Bt, 256, As, Bs, t, wm, wn, lane, acc);
    int lm = lane & 15, lq = lane >> 4;
    #pragma unroll
    for (int tn = 0; tn < 4; ++tn) {
        int n = wn * 64 + tn * 16 + lm;
        float bn = bias[n];
        #pragma unroll
        for (int tm = 0; tm < 4; ++tm) {
            int mb = m0 + wm * 64 + tm * 16 + lq * 4;
            #pragma unroll
            for (int rr = 0; rr < 4; ++rr)
                H2[(size_t)(mb + rr) * 256 + n] = f2b(fmaxf(acc[tm][tn][rr] + bn, 0.f));
        }
    }
}

// conv1 big: Y1 = X @ C1W^T + b, M=25600, N=512, K=512 -> grid(100,2), 1024 thr, fused stats
__global__ __launch_bounds__(1024) void k_gemm_conv1_big(const unsigned short* __restrict__ A,
                                                         const unsigned short* __restrict__ Bt,
                                                         const float* __restrict__ bias,
                                                         unsigned short* __restrict__ Y,
                                                         float* __restrict__ st) {
    __shared__ unsigned short As[2][256 * 32], Bs[2][256 * 32];
    int t = threadIdx.x, lane = t & 63, wid = t >> 6;
    int wm = wid >> 2, wn = wid & 3;
    int m0 = blockIdx.x * 256, n0 = blockIdx.y * 256;
    f32x4 acc[4][4] = {};
    gemm_loop_big<16>(A + (size_t)m0 * 512, 512, Bt + (size_t)n0 * 512, 512,
                      As, Bs, t, wm, wn, lane, acc);
    int lm = lane & 15, lq = lane >> 4;
    #pragma unroll
    for (int tn = 0; tn < 4; ++tn) {
        int n = n0 + wn * 64 + tn * 16 + lm;
        float bn = bias[n];
        float s1 = 0.f, s2 = 0.f;
        #pragma unroll
        for (int tm = 0; tm < 4; ++tm) {
            int mb = m0 + wm * 64 + tm * 16 + lq * 4;
            #pragma unroll
            for (int rr = 0; rr < 4; ++rr) {
                float v = acc[tm][tn][rr] + bn;
                Y[(size_t)(mb + rr) * 512 + n] = f2b(v);
                s1 += v; s2 += v * v;
            }
        }
        s1 += __shfl_xor(s1, 16); s1 += __shfl_xor(s1, 32);
        s2 += __shfl_xor(s2, 16); s2 += __shfl_xor(s2, 32);
        if (lq == 0) { atomicAdd(&st[n], s1); atomicAdd(&st[512 + n], s2); }
    }
}

// ================= 256-thread GEMM (single-buffer, r11-validated) =================
__device__ __forceinline__ void stage_tile(const unsigned short* __restrict__ g, int ld,
                                           unsigned short* lds, int wave, int lane) {
    #pragma unroll
    for (int j = 0; j < 4; ++j) {
        int idx = wave * 256 + j * 64 + lane;      // chunk slot index 0..1023
        int r = idx >> 3;
        int cs = idx & 7;
        int cl = cs ^ (r & 7);                     // logical chunk this slot holds
        __builtin_amdgcn_global_load_lds(
            (const __attribute__((address_space(1))) void*)(g + (size_t)r * ld + cl * 8),
            (__attribute__((address_space(3))) void*)(lds + wave * 2048 + j * 512),
            16, 0, 0);
    }
}

__device__ __forceinline__ frag8 frag_read(const unsigned short* lds, int row, int chunk) {
    return *(const frag8*)(lds + row * 64 + ((chunk ^ (row & 7)) << 3));
}

__device__ __forceinline__ void mma_tile(const unsigned short* As, const unsigned short* Bs,
                                         int wm, int wn, int lane, f32x4 (&acc)[4][4]) {
    int lm = lane & 15, lq = lane >> 4;
    #pragma unroll
    for (int kk = 0; kk < 2; ++kk) {
        frag8 a[4], b[4];
        #pragma unroll
        for (int t = 0; t < 4; ++t) a[t] = frag_read(As, wm * 64 + t * 16 + lm, kk * 4 + lq);
        #pragma unroll
        for (int t = 0; t < 4; ++t) b[t] = frag_read(Bs, wn * 64 + t * 16 + lm, kk * 4 + lq);
        #pragma unroll
        for (int tm = 0; tm < 4; ++tm)
            #pragma unroll
            for (int tn = 0; tn < 4; ++tn)
                acc[tm][tn] = __builtin_amdgcn_mfma_f32_16x16x32_bf16(a[tm], b[tn], acc[tm][tn], 0, 0, 0);
    }
}

// ---------------- pe3: X = bf16(samp + H2 @ W3T^T + b3) ----------------
__global__ __launch_bounds__(256) void k_gemm_pe3(const unsigned short* __restrict__ A,
                                                  const unsigned short* __restrict__ Bt,
                                                  const float* __restrict__ bias,
                                                  const unsigned short* __restrict__ samp,
                                                  unsigned short* __restrict__ X) {
    __shared__ unsigned short As[BM * BK], Bs[BN * BK];
    int lane = threadIdx.x & 63, wave = threadIdx.x >> 6;
    int wm = wave >> 1, wn = wave & 1;
    int m0 = blockIdx.x * BM;
    f32x4 acc[4][4] = {};
    for (int kt = 0; kt < 4; ++kt) {
        stage_tile(A + (size_t)m0 * 256 + kt * BK, 256, As, wave, lane);
        stage_tile(Bt + (size_t)kt * BK, 256, Bs, wave, lane);
        __syncthreads();
        mma_tile(As, Bs, wm, wn, lane, acc);
        __syncthreads();
    }
    int lm = lane & 15, lq = lane >> 4;
    #pragma unroll
    for (int tn = 0; tn < 4; ++tn) {
        int n = wn * 64 + tn * 16 + lm;
        float bn = bias[n];
        #pragma unroll
        for (int tm = 0; tm < 4; ++tm) {
            int mb = m0 + wm * 64 + tm * 16 + lq * 4;
            #pragma unroll
            for (int rr = 0; rr < 4; ++rr) {
                size_t off = (size_t)(mb + rr) * 128 + n;
                X[off] = f2b(acc[tm][tn][rr] + bn + b2f_bits(samp[off]));
            }
        }
    }
}

// ---------------- conv2 GEMM -> bf16 Y + f32 inorm stats ----------------
template <int K, bool STATS>
__global__ __launch_bounds__(256) void k_gemm_conv(const unsigned short* __restrict__ A,
                                                   const unsigned short* __restrict__ Bt,
                                                   const float* __restrict__ bias,
                                                   unsigned short* __restrict__ Y, int ldY,
                                                   float* __restrict__ st, int C) {
    __shared__ unsigned short As[BM * BK], Bs[BN * BK];
    int lane = threadIdx.x & 63, wave = threadIdx.x >> 6;
    int wm = wave >> 1, wn = wave & 1;
    int m0 = blockIdx.x * BM, n0 = blockIdx.y * BN;
    f32x4 acc[4][4] = {};
    for (int kt = 0; kt < K / BK; ++kt) {
        stage_tile(A + (size_t)m0 * K + kt * BK, K, As, wave, lane);
        stage_tile(Bt + (size_t)n0 * K + kt * BK, K, Bs, wave, lane);
        __syncthreads();
        mma_tile(As, Bs, wm, wn, lane, acc);
        __syncthreads();
    }
    int lm = lane & 15, lq = lane >> 4;
    #pragma unroll
    for (int tn = 0; tn < 4; ++tn) {
        int n = n0 + wn * 64 + tn * 16 + lm;
        float bn = bias[n];
        float s1 = 0.f, s2 = 0.f;
        #pragma unroll
        for (int tm = 0; tm < 4; ++tm) {
            int mb = m0 + wm * 64 + tm * 16 + lq * 4;
            #pragma unroll
            for (int rr = 0; rr < 4; ++rr) {
                float v = acc[tm][tn][rr] + bn;
                Y[(size_t)(mb + rr) * ldY + n] = f2b(v);
                if (STATS) { s1 += v; s2 += v * v; }
            }
        }
        if (STATS) {
            s1 += __shfl_xor(s1, 16); s1 += __shfl_xor(s1, 32);
            s2 += __shfl_xor(s2, 16); s2 += __shfl_xor(s2, 32);
            if (lq == 0) { atomicAdd(&st[n], s1); atomicAdd(&st[C + n], s2); }
        }
    }
}

// ---------------- conv3 -> out f32 [128][25600] ----------------
__global__ __launch_bounds__(256) void k_gemm_conv3(const unsigned short* __restrict__ A,
                                                    const unsigned short* __restrict__ Bt,
                                                    const float* __restrict__ bias,
                                                    float* __restrict__ out) {
    __shared__ unsigned short As[BM * BK], Bs[BN * BK];
    int lane = threadIdx.x & 63, wave = threadIdx.x >> 6;
    int wm = wave >> 1, wn = wave & 1;
    int m0 = blockIdx.x * BM;
    f32x4 acc[4][4] = {};
    for (int kt = 0; kt < 2; ++kt) {
        stage_tile(A + (size_t)m0 * 128 + kt * BK, 128, As, wave, lane);
        stage_tile(Bt + (size_t)kt * BK, 128, Bs, wave, lane);
        __syncthreads();
        mma_tile(As, Bs, wm, wn, lane, acc);
        __syncthreads();
    }
    int lm = lane & 15, lq = lane >> 4;
    #pragma unroll
    for (int tn = 0; tn < 4; ++tn) {
        int n = wn * 64 + tn * 16 + lm;
        float bn = bias[n];
        #pragma unroll
        for (int tm = 0; tm < 4; ++tm) {
            int mb = m0 + wm * 64 + tm * 16 + lq * 4;
            float4 pk;
            pk.x = acc[tm][tn][0] + bn;
            pk.y = acc[tm][tn][1] + bn;
            pk.z = acc[tm][tn][2] + bn;
            pk.w = acc[tm][tn][3] + bn;
            *(float4*)(out + (size_t)n * 25600 + mb) = pk;
        }
    }
}

// -------- norm+gelu with inline finalize (mean/rsqrt derived from raw sums) --------
__global__ void k_normgelu8f(const unsigned short* __restrict__ Y, const float* __restrict__ st,
                             unsigned short* __restrict__ X2, int Cmask, int C, float inv_n,
                             int total8) {
    int i8 = blockIdx.x * 256 + threadIdx.x;
    if (i8 >= total8) return;
    int e0 = i8 * 8;
    int c = e0 & Cmask;
    uint4 y = *(const uint4*)(Y + e0);
    float4 s1a = *(const float4*)(st + c);
    float4 s1b = *(const float4*)(st + c + 4);
    float4 s2a = *(const float4*)(st + C + c);
    float4 s2b = *(const float4*)(st + C + c + 4);
    float mu[8] = { s1a.x * inv_n, s1a.y * inv_n, s1a.z * inv_n, s1a.w * inv_n,
                    s1b.x * inv_n, s1b.y * inv_n, s1b.z * inv_n, s1b.w * inv_n };
    float sq[8] = { s2a.x, s2a.y, s2a.z, s2a.w, s2b.x, s2b.y, s2b.z, s2b.w };
    float rs[8];
    #pragma unroll
    for (int j = 0; j < 8; ++j) rs[j] = rsqrtf(sq[j] * inv_n - mu[j] * mu[j] + 1e-5f);
    const float is2 = 0.70710678118654752f;
    unsigned int yw[4] = {y.x, y.y, y.z, y.w};
    unsigned int ow[4];
    #pragma unroll
    for (int j = 0; j < 4; ++j) {
        float v0 = (b2f_bits((unsigned short)(yw[j] & 0xffffu)) - mu[j * 2]) * rs[j * 2];
        float v1 = (b2f_bits((unsigned short)(yw[j] >> 16)) - mu[j * 2 + 1]) * rs[j * 2 + 1];
        float g0 = 0.5f * v0 * (1.f + erff(v0 * is2));
        float g1 = 0.5f * v1 * (1.f + erff(v1 * is2));
        ow[j] = (uint32_t)f2b(g0) | ((uint32_t)f2b(g1) << 16);
    }
    *(uint4*)(X2 + e0) = make_uint4(ow[0], ow[1], ow[2], ow[3]);
}

// ---------------- launch ----------------
extern "C" void kernel_launch(void* const* d_in, const int* in_sizes, int n_in,
                              void* d_out, int out_size, void* d_ws, size_t ws_size,
                              hipStream_t stream) {
    (void)in_sizes; (void)n_in; (void)out_size; (void)ws_size;
    const float* feat = (const float*)d_in[0];
    const float* l2i  = (const float*)d_in[1];
    const float* bev  = (const float*)d_in[2];
    const float* pw1  = (const float*)d_in[3];
    const float* pb1  = (const float*)d_in[4];
    const float* pw2  = (const float*)d_in[5];
    const float* pb2  = (const float*)d_in[6];
    const float* pw3  = (const float*)d_in[7];
    const float* pb3  = (const float*)d_in[8];
    const float* c1w  = (const float*)d_in[9];
    const float* c1b  = (const float*)d_in[10];
    const float* c2w  = (const float*)d_in[11];
    const float* c2b  = (const float*)d_in[12];
    const float* c3w  = (const float*)d_in[13];
    const float* c3b  = (const float*)d_in[14];
    float* outp = (float*)d_out;
    char* ws = (char*)d_ws;

    // ---- workspace layout (bytes), peak ~148.6 MB ----
    unsigned short* featT = (unsigned short*)(ws + 0);          //  4,325,376 + 23,040 pad
    unsigned short* W2Tb  = (unsigned short*)(ws + 4348416);    //    131,072 [256][256] bf16 [o][k]
    unsigned short* W3Tb  = (unsigned short*)(ws + 4479488);    //     65,536 [128][256]
    unsigned short* C1Wb  = (unsigned short*)(ws + 4545024);    //    524,288 [512][512]
    unsigned short* C2Wb  = (unsigned short*)(ws + 5069312);    //    131,072 [128][512]
    unsigned short* C3Wb  = (unsigned short*)(ws + 5200384);    //     32,768 [128][128]
    float* stats          = (float*)(ws + 5233152);             //     10,240
    int*    poff          = (int*)(ws + 5247488);               //  2,457,600 [6][102400]
    float4* pwts          = (float4*)(ws + 7705088);            //  9,830,400 [6][102400]
    char* BUF1 = ws + 17535488;   // 52,428,800: H1 bf16 -> X bf16 -> Y2 bf16 + X3 bf16
    char* BUF2 = ws + 69964288;   // 52,428,800: H2 bf16 -> Y1 bf16 (26 MB)
    char* BUF3 = ws + 122393088;  // 26,214,400: samp bf16 -> X2 bf16
    // total = 148,607,488

    float* st512 = stats;          // 1024 f (sums + sumsq)
    float* st128 = stats + 2048;   // 256 f

    unsigned short* H1   = (unsigned short*)BUF1;
    unsigned short* H2   = (unsigned short*)BUF2;
    unsigned short* samp = (unsigned short*)BUF3;
    unsigned short* X    = (unsigned short*)BUF1;               // after H1 dead (pe3)
    unsigned short* Y1   = (unsigned short*)BUF2;               // after H2 dead (conv1)
    unsigned short* X2   = (unsigned short*)BUF3;               // after samp dead (normgelu1)
    unsigned short* Y2   = (unsigned short*)BUF1;               // after X dead (conv2)
    unsigned short* X3   = (unsigned short*)(BUF1 + 6553600);

    // merged prep: pe1 + projection + featT transpose + casts + stats zero
    k_prep<<<29993, 256, 0, stream>>>(feat, pw2, pw3, c1w, c2w, c3w, pw1, pb1, l2i, bev,
                                      featT, W2Tb, W3Tb, C1Wb, C2Wb, C3Wb, H1, stats,
                                      poff, pwts);

    // gather-only sampling
    k_sample2<<<25600, 256, 0, stream>>>(featT, poff, pwts, samp);

    // PE MLP
    k_gemm_pe2_big<<<400, 1024, 0, stream>>>(H1, W2Tb, pb2, H2);
    k_gemm_pe3<<<dim3(800, 1), 256, 0, stream>>>(H2, W3Tb, pb3, samp, X);

    // conv1 (512->512) + fused stats, then norm+gelu (inline finalize)
    k_gemm_conv1_big<<<dim3(100, 2), 1024, 0, stream>>>(X, C1Wb, c1b, Y1, st512);
    k_normgelu8f<<<6400, 256, 0, stream>>>(Y1, st512, X2, 511, 512, 1.f / 25600.f, 1638400);

    // conv2 (512->128) + fused stats, then norm+gelu (inline finalize)
    k_gemm_conv<512, true><<<dim3(200, 1), 256, 0, stream>>>(X2, C2Wb, c2b, Y2, 128, st128, 128);
    k_normgelu8f<<<1600, 256, 0, stream>>>(Y2, st128, X3, 127, 128, 1.f / 25600.f, 409600);

    // conv3 (128->128) -> out f32 [128][25600]
    k_gemm_conv3<<<dim3(200, 1), 256, 0, stream>>>(X3, C3Wb, c3b, outp);
}